// Round 8
// baseline (338.389 us; speedup 1.0000x reference)
//
#include <hip/hip_runtime.h>
#include <cstddef>

#define NPB  4096            // points per batch
#define KNB  20              // neighbors
#define NB   8               // batches
#define NPTS (NB * NPB)      // 32768 total points
#define PPB  32              // points per knn block
#define SEGW 512             // candidates per wave-segment (256 per half)

// ---------------------------------------------------------------------------
// Kernel A+P: pack (x,y,z,xx) float4 (512 KB, L2-resident) + block 0 folds
// BN into conv weights. xx arithmetic identical to reference numpy fp32.
// ---------------------------------------------------------------------------
__global__ __launch_bounds__(256) void pack_prep_kernel(
    const float* __restrict__ x, float4* __restrict__ xp,
    const float* __restrict__ w1, const float* __restrict__ b1,
    const float* __restrict__ g1, const float* __restrict__ be1,
    const float* __restrict__ rm1, const float* __restrict__ rv1,
    const float* __restrict__ w2, const float* __restrict__ b2,
    const float* __restrict__ g2, const float* __restrict__ be2,
    const float* __restrict__ rm2, const float* __restrict__ rv2,
    float* __restrict__ w1f, float* __restrict__ w2f, float* __restrict__ w2b)
{
    const int tid = threadIdx.x;
    const int g = blockIdx.x * 256 + tid;
    const int b = g >> 12, n = g & (NPB - 1);
    const float* xb = x + (size_t)b * 3 * NPB;
    float a0 = xb[n], a1 = xb[NPB + n], a2 = xb[2 * NPB + n];
    float xx = __fadd_rn(__fadd_rn(__fmul_rn(a0, a0), __fmul_rn(a1, a1)),
                         __fmul_rn(a2, a2));
    xp[g] = make_float4(a0, a1, a2, xx);

    if (blockIdx.x == 0) {
        if (tid < 64) {
            float sc1 = g1[tid] * rsqrtf(rv1[tid] + 1e-5f);
            float sh1 = be1[tid] - rm1[tid] * sc1;
#pragma unroll
            for (int j = 0; j < 6; ++j) w1f[tid * 8 + j] = sc1 * w1[tid * 6 + j];
            w1f[tid * 8 + 6] = sc1 * b1[tid] + sh1;
            w1f[tid * 8 + 7] = 0.f;
            float sc2 = g2[tid] * rsqrtf(rv2[tid] + 1e-5f);
            w2b[tid] = sc2 * b2[tid] + (be2[tid] - rm2[tid] * sc2);
        }
        for (int i = tid; i < 64 * 128; i += 256) {
            int c = i >> 6, o = i & 63;
            float sc2 = g2[o] * rsqrtf(rv2[o] + 1e-5f);
            w2f[i] = sc2 * w2[o * 128 + c];
        }
    }
}

// ---------------------------------------------------------------------------
// Kernel B: exact top-20 SET per point (pooling is order-invariant).
// Block = 512 thr = 32 points x 16 half-entities (256 cands each); wave wv
// = lanes 0-31 scanning [wv*512,+256) and lanes 32-63 scanning [+256,+512).
// Grid = 1024 blocks -> 4 blocks/CU, 32 waves/CU.
// Phase A: per-entity top-20 VALUES (direct insert of first 24, then
// buffered pushes with racy cross-entity threshold sharing); in-wave LDS
// ping-pong merge of the two halves -> 8 per-wave lists; redundant 8-way
// merge -> exact t (20th largest). Phase B: rescan, survivors d>=t push
// key=(tie?4096:0)|idx into an LDS-atomic pool (order nondeterministic);
// one wave selection-sorts keys ascending -> deterministic reference order
// (strict by index, then ties by index). Identical fp32 dist arithmetic.
// ---------------------------------------------------------------------------
union KSMem {
    float buf[8][512];          // 16 KB push buffers [slot][tid]
    float vals[8][KNB][PPB];    // 20 KB per-wave merged lists [wave][j][pt]
    int   pool[32][PPB];        //  4 KB survivor keys [slot][pt]
};

__global__ __launch_bounds__(512, 8) void knn_kernel(const float4* __restrict__ xp,
                                                     int* __restrict__ knn_t) {
    __shared__ KSMem sm;
    __shared__ float share[16][PPB];    // 2 KB entity vmins [ent][pt]
    __shared__ int   pcnt[PPB];

    const int tid  = threadIdx.x;
    const int wv   = __builtin_amdgcn_readfirstlane(tid >> 6);
    const int lane = tid & 63;
    const int pt   = lane & 31;
    const int ent  = tid >> 5;               // 0..15
    const int g0   = blockIdx.x * PPB;
    const int b    = g0 >> 12;

    ((float*)share)[tid] = -INFINITY;        // 16*32 = 512 entries
    __syncthreads();

    const float4 me = xp[g0 + pt];
    const float cx = me.x, cy = me.y, cz = me.z, xxn = me.w;

    auto dist = [&](float4 q) -> float {
        float inner = __fadd_rn(__fadd_rn(__fmul_rn(cx, q.x), __fmul_rn(cy, q.y)),
                                __fmul_rn(cz, q.z));
        return __fsub_rn(__fsub_rn(__fmul_rn(2.0f, inner), xxn), q.w);
    };

    float vals[KNB];
#pragma unroll
    for (int j = 0; j < KNB; ++j) vals[j] = -INFINITY;

    auto ins20 = [&](float cv) {
#pragma unroll
        for (int q = 0; q < KNB; ++q) {      // 2-op step: max/min
            float nv = fmaxf(cv, vals[q]);
            cv       = fminf(cv, vals[q]);
            vals[q]  = nv;
        }
    };

    const int     hoff  = (lane >> 5) << 8;          // 0 or 256
    const float4* cand  = xp + (b << 12) + wv * SEGW + hoff;
    const int     ibase = wv * SEGW + hoff;

    // warm-up: direct insert of first 24 candidates (makes vmin real fast)
#pragma unroll 1
    for (int i = 0; i < 24; i += 4) {
        float d0 = dist(cand[i]),     d1 = dist(cand[i + 1]);
        float d2 = dist(cand[i + 2]), d3 = dist(cand[i + 3]);
        ins20(d0); ins20(d1); ins20(d2); ins20(d3);
    }
    float vmin = vals[KNB - 1];
    float thr  = vmin;
    int   cnt  = 0;

    auto flush = [&]() {
#pragma unroll
        for (int j = 0; j < 8; ++j) {
            if (!__any(j < cnt)) break;
            float cv = (j < cnt) ? sm.buf[j][tid] : -INFINITY;
            if (__any(cv > vals[KNB - 1])) ins20(cv);
        }
        cnt  = 0;
        vmin = vals[KNB - 1];
        thr  = fmaxf(thr, vmin);
    };

    // rest of first chunk (no share refresh yet)
#pragma unroll 1
    for (int i = 24; i < 64; i += 4) {
#pragma unroll
        for (int u = 0; u < 4; ++u) {
            float d = dist(cand[i + u]);
            if (d > thr) { sm.buf[cnt][tid] = d; ++cnt; }
        }
        if (__any(cnt >= 5)) flush();        // cap: 4 + 4 = 8 slots
    }

    // main scan, cross-entity threshold refresh every 64 candidates
#pragma unroll 1
    for (int ii = 64; ii < 256; ii += 64) {
        share[ent][pt] = vmin;               // racy: stale = safe lower bound
        float mx = share[0][pt];
#pragma unroll
        for (int w = 1; w < 16; ++w) mx = fmaxf(mx, share[w][pt]);
        thr = fmaxf(thr, mx);
#pragma unroll 1
        for (int i = ii; i < ii + 64; i += 4) {
#pragma unroll
            for (int u = 0; u < 4; ++u) {
                float d = dist(cand[i + u]);
                if (d > thr) { sm.buf[cnt][tid] = d; ++cnt; }
            }
            if (__any(cnt >= 5)) flush();
        }
    }
    flush();
    __syncthreads();                         // retire push buffers (alias vals)

    // in-wave half-merge via LDS ping-pong (wave-private region, no barrier)
    if (lane >= 32) {
#pragma unroll
        for (int j = 0; j < KNB; ++j) sm.vals[wv][j][pt] = vals[j];
    }
    if (lane < 32) {
#pragma unroll
        for (int j = 0; j < KNB; ++j) {      // other list is sorted desc
            float cv = sm.vals[wv][j][pt];
            if (!__any(cv > vals[KNB - 1])) break;
            ins20(cv);
        }
#pragma unroll
        for (int j = 0; j < KNB; ++j) sm.vals[wv][j][pt] = vals[j];
    }
    __syncthreads();

    // redundant 8-way merge of per-wave lists -> exact t (20th largest)
    float t = -INFINITY;
    {
        int p0 = 0, p1 = 0, p2 = 0, p3 = 0, p4 = 0, p5 = 0, p6 = 0, p7 = 0;
#pragma unroll 1
        for (int k = 0; k < KNB; ++k) {
            float e0 = sm.vals[0][p0][pt], e1 = sm.vals[1][p1][pt];
            float e2 = sm.vals[2][p2][pt], e3 = sm.vals[3][p3][pt];
            float e4 = sm.vals[4][p4][pt], e5 = sm.vals[5][p5][pt];
            float e6 = sm.vals[6][p6][pt], e7 = sm.vals[7][p7][pt];
            float bv = e0; int bs = 0;
            if (e1 > bv) { bv = e1; bs = 1; }
            if (e2 > bv) { bv = e2; bs = 2; }
            if (e3 > bv) { bv = e3; bs = 3; }
            if (e4 > bv) { bv = e4; bs = 4; }
            if (e5 > bv) { bv = e5; bs = 5; }
            if (e6 > bv) { bv = e6; bs = 6; }
            if (e7 > bv) { bv = e7; bs = 7; }
            t = bv;
            p0 += (bs == 0); p1 += (bs == 1); p2 += (bs == 2); p3 += (bs == 3);
            p4 += (bs == 4); p5 += (bs == 5); p6 += (bs == 6); p7 += (bs == 7);
        }
    }
    __syncthreads();                         // retire vals (alias pool)

    ((int*)sm.pool)[tid]       = 0x7fffffff; // init 1024 pool slots
    ((int*)sm.pool)[tid + 512] = 0x7fffffff;
    if (tid < PPB) pcnt[tid] = 0;
    __syncthreads();

    // phase B: survivors d >= t -> pool (LDS atomic; order fixed by sort)
#pragma unroll 1
    for (int i = 0; i < 256; i += 8) {
#pragma unroll
        for (int u = 0; u < 8; ++u) {
            float d = dist(cand[i + u]);
            if (d >= t) {
                int slot = atomicAdd(&pcnt[pt], 1);
                int key  = (ibase + i + u) | ((d > t) ? 0 : 4096);
                if (slot < 32) sm.pool[slot][pt] = key;
            }
        }
    }
    __syncthreads();

    // one wave selection-sorts keys ascending and writes transposed knn_t
    if (tid < PPB) {
#pragma unroll 1
        for (int k = 0; k < KNB; ++k) {
            int best = 0x7fffffff, bj = 0;
#pragma unroll
            for (int j = 0; j < 32; ++j) {
                int v = sm.pool[j][tid];
                if (v < best) { best = v; bj = j; }
            }
            sm.pool[bj][tid] = 0x7fffffff;
            knn_t[k * NPTS + g0 + tid] = best & 4095;
        }
    }
}

// ---------------------------------------------------------------------------
// Kernel C: fused gather + conv1+BN+ReLU + max/mean pool + conv2+BN+ReLU.
// Block = 512 thr = 64 points x 8 channel-eighth waves (lane = point).
// (unchanged from round 6 — validated)
// ---------------------------------------------------------------------------
__global__ __launch_bounds__(512, 4) void fuse_kernel(
    const float4* __restrict__ xp, const int* __restrict__ knn_t,
    const float* __restrict__ w1f, const float* __restrict__ w2f,
    const float* __restrict__ w2b, float* __restrict__ out)
{
    __shared__ float cat[128 * 64];     // 32KB: [c][pt], c<64: m1, c>=64: m2
    __shared__ float dif[KNB][3][64];   // 15KB: [k][coord][pt]

    const int tid  = threadIdx.x;
    const int wave = __builtin_amdgcn_readfirstlane(tid >> 6);
    const int lane = tid & 63;
    const int g0   = blockIdx.x * 64;
    const int b    = g0 >> 12, n0 = g0 & (NPB - 1);

#pragma unroll
    for (int r = 0; r < 3; ++r) {
        int p = tid + r * 512;
        if (p < KNB * 64) {
            int k = p >> 6, pt = p & 63;
            int nb = knn_t[k * NPTS + g0 + pt];          // coalesced
            float4 nq = xp[(b << 12) + nb];              // scattered (spread)
            float4 cq = xp[g0 + pt];                     // L1-hot
            dif[k][0][pt] = __fsub_rn(nq.x, cq.x);
            dif[k][1][pt] = __fsub_rn(nq.y, cq.y);
            dif[k][2][pt] = __fsub_rn(nq.z, cq.z);
        }
    }
    __syncthreads();

    const float4 me = xp[g0 + lane];
    const float c0 = me.x, c1 = me.y, c2 = me.z;
    float dx[KNB], dy[KNB], dz[KNB];
#pragma unroll
    for (int k = 0; k < KNB; ++k) {
        dx[k] = dif[k][0][lane];
        dy[k] = dif[k][1][lane];
        dz[k] = dif[k][2][lane];
    }

    const float4* w1fv = (const float4*)w1f;
#pragma unroll 1
    for (int cc = 0; cc < 8; ++cc) {
        int c = wave * 8 + cc;                           // uniform -> s_load
        float4 wa = w1fv[c * 2];
        float4 wb = w1fv[c * 2 + 1];
        float base = wb.z + wa.w * c0 + wb.x * c1 + wb.y * c2;
        float m1 = -INFINITY, s = 0.f;
#pragma unroll
        for (int k = 0; k < KNB; ++k) {
            float h = fmaf(dz[k], wa.z, fmaf(dy[k], wa.y, fmaf(dx[k], wa.x, base)));
            float r = fmaxf(0.f, h);
            m1 = fmaxf(m1, r);
            s += r;
        }
        cat[c * 64 + lane]        = m1;
        cat[(64 + c) * 64 + lane] = s / 20.0f;
    }
    __syncthreads();

    const size_t SEC = (size_t)NB * 64 * NPB;

#pragma unroll 1
    for (int q = 0; q < 16; ++q) {
        int r  = wave * 16 + q;
        int ch = r & 63;
        float* dst = out + SEC * (1 + (r >> 6)) + ((size_t)b * 64 + ch) * NPB + n0;
        dst[lane] = cat[r * 64 + lane];
    }

    const int ob = wave * 8;                    // uniform -> s_load weights
    float acc[8];
#pragma unroll
    for (int j = 0; j < 8; ++j) acc[j] = w2b[ob + j];
#pragma unroll 4
    for (int c = 0; c < 128; ++c) {
        float v = cat[c * 64 + lane];
        const float4* wr = (const float4*)(w2f + c * 64 + ob);
        float4 q0 = wr[0], q1 = wr[1];
        acc[0] = fmaf(v, q0.x, acc[0]);  acc[1] = fmaf(v, q0.y, acc[1]);
        acc[2] = fmaf(v, q0.z, acc[2]);  acc[3] = fmaf(v, q0.w, acc[3]);
        acc[4] = fmaf(v, q1.x, acc[4]);  acc[5] = fmaf(v, q1.y, acc[5]);
        acc[6] = fmaf(v, q1.z, acc[6]);  acc[7] = fmaf(v, q1.w, acc[7]);
    }
#pragma unroll
    for (int j = 0; j < 8; ++j) acc[j] = fmaxf(0.f, acc[j]);

    __syncthreads();
#pragma unroll
    for (int j = 0; j < 8; ++j) cat[(ob + j) * 64 + lane] = acc[j];
    __syncthreads();
#pragma unroll 1
    for (int q = 0; q < 8; ++q) {
        int oo = wave * 8 + q;
        out[((size_t)b * 64 + oo) * NPB + n0 + lane] = cat[oo * 64 + lane];
    }
}

extern "C" void kernel_launch(void* const* d_in, const int* in_sizes, int n_in,
                              void* d_out, int out_size, void* d_ws, size_t ws_size,
                              hipStream_t stream) {
    const float* x   = (const float*)d_in[0];
    const float* w1  = (const float*)d_in[1];
    const float* b1  = (const float*)d_in[2];
    const float* g1  = (const float*)d_in[3];
    const float* be1 = (const float*)d_in[4];
    const float* rm1 = (const float*)d_in[5];
    const float* rv1 = (const float*)d_in[6];
    const float* w2  = (const float*)d_in[7];
    const float* b2  = (const float*)d_in[8];
    const float* g2  = (const float*)d_in[9];
    const float* be2 = (const float*)d_in[10];
    const float* rm2 = (const float*)d_in[11];
    const float* rv2 = (const float*)d_in[12];

    char*   ws    = (char*)d_ws;
    float4* xp    = (float4*)ws;                                // 512 KB
    int*    knn_t = (int*)(ws + 512 * 1024);                    // 2.62 MB
    float*  w1f   = (float*)(ws + 512 * 1024 + (size_t)KNB * NPTS * 4);
    float*  w2f   = w1f + 64 * 8;
    float*  w2b   = w2f + 64 * 128;

    pack_prep_kernel<<<NPTS / 256, 256, 0, stream>>>(
        x, xp, w1, b1, g1, be1, rm1, rv1, w2, b2, g2, be2, rm2, rv2,
        w1f, w2f, w2b);
    knn_kernel<<<NPTS / PPB, 512, 0, stream>>>(xp, knn_t);
    fuse_kernel<<<NPTS / 64, 512, 0, stream>>>(xp, knn_t, w1f, w2f, w2b,
                                               (float*)d_out);
}

// Round 9
// 293.380 us; speedup vs baseline: 1.1534x; 1.1534x over previous
//
#include <hip/hip_runtime.h>
#include <cstddef>

#define NPB  4096            // points per batch
#define KNB  20              // neighbors
#define NB   8               // batches
#define NPTS (NB * NPB)      // 32768 total points
#define NSEG 8               // segment-waves per block
#define SEGW 512             // candidates per segment
#define NSLOT 12             // push-buffer slots per thread

// ---------------------------------------------------------------------------
// Kernel A+P: pack (x,y,z,xx) float4 (512 KB, L2-resident) + block 0 folds
// BN into conv weights. xx arithmetic identical to reference numpy fp32.
// ---------------------------------------------------------------------------
__global__ __launch_bounds__(256) void pack_prep_kernel(
    const float* __restrict__ x, float4* __restrict__ xp,
    const float* __restrict__ w1, const float* __restrict__ b1,
    const float* __restrict__ g1, const float* __restrict__ be1,
    const float* __restrict__ rm1, const float* __restrict__ rv1,
    const float* __restrict__ w2, const float* __restrict__ b2,
    const float* __restrict__ g2, const float* __restrict__ be2,
    const float* __restrict__ rm2, const float* __restrict__ rv2,
    float* __restrict__ w1f, float* __restrict__ w2f, float* __restrict__ w2b)
{
    const int tid = threadIdx.x;
    const int g = blockIdx.x * 256 + tid;
    const int b = g >> 12, n = g & (NPB - 1);
    const float* xb = x + (size_t)b * 3 * NPB;
    float a0 = xb[n], a1 = xb[NPB + n], a2 = xb[2 * NPB + n];
    float xx = __fadd_rn(__fadd_rn(__fmul_rn(a0, a0), __fmul_rn(a1, a1)),
                         __fmul_rn(a2, a2));
    xp[g] = make_float4(a0, a1, a2, xx);

    if (blockIdx.x == 0) {
        if (tid < 64) {
            float sc1 = g1[tid] * rsqrtf(rv1[tid] + 1e-5f);
            float sh1 = be1[tid] - rm1[tid] * sc1;
#pragma unroll
            for (int j = 0; j < 6; ++j) w1f[tid * 8 + j] = sc1 * w1[tid * 6 + j];
            w1f[tid * 8 + 6] = sc1 * b1[tid] + sh1;
            w1f[tid * 8 + 7] = 0.f;
            float sc2 = g2[tid] * rsqrtf(rv2[tid] + 1e-5f);
            w2b[tid] = sc2 * b2[tid] + (be2[tid] - rm2[tid] * sc2);
        }
        for (int i = tid; i < 64 * 128; i += 256) {
            int c = i >> 6, o = i & 63;
            float sc2 = g2[o] * rsqrtf(rv2[o] + 1e-5f);
            w2f[i] = sc2 * w2[o * 128 + c];
        }
    }
}

// ---------------------------------------------------------------------------
// Kernel B+C merged: exact top-20 SET per point (R7-validated scan) followed
// in-block by the fused gather+conv1+BN+ReLU+pool+conv2+BN+ReLU epilogue.
// Block = 512 thr = 64 points x 8 segment-waves (512 wave-uniform cands
// each -> s_load broadcast). Phase A: warm-up direct insert (20), buffered
// value-only pushes, racy cross-wave threshold sharing, 8-way merge -> exact
// t. Phase B: rescan, survivors (idx | strict-bit); wave0 assembles the
// reference-ordered set into LDS. Fuse stage reads indices straight from
// LDS (no global knn round-trip), stages neighbor difs cooperatively, then
// conv1 (8 ch/wave) -> cat[128][64] -> row writes + conv2 -> final write.
// LDS 55.3 KB time-multiplexed union; identical fp32 dist arithmetic.
// ---------------------------------------------------------------------------
union KSMem {
    float buf[NSLOT][512];          // 24 KB scan push buffers [slot][tid]
    float vals[NSEG][KNB][64];      // 40 KB sorted partial lists [wave][j][pt]
    struct {
        int list[NSEG][64][21];     // 42 KB survivors idx|(strict<<31)
        int cnt[NSEG][64];          //  2 KB
    } b;                            // 44 KB
    struct {
        float cat[128 * 64];        // 32 KB [c][pt]: c<64 m1, c>=64 m2
        float dif[KNB][3][64];      // 15 KB [k][coord][pt]
    } f;                            // 47 KB  (union = 47 KB)
};

__global__ __launch_bounds__(512, 4) void knnfuse_kernel(
    const float4* __restrict__ xp,
    const float* __restrict__ w1f, const float* __restrict__ w2f,
    const float* __restrict__ w2b, float* __restrict__ out)
{
    __shared__ KSMem sm;
    __shared__ float share[NSEG][64];   // 2 KB cross-wave vmins
    __shared__ int   outk[KNB][64];     // 5 KB final neighbor idx [k][pt]

    const int tid  = threadIdx.x;
    const int wv   = __builtin_amdgcn_readfirstlane(tid >> 6);
    const int lane = tid & 63;
    const int g0   = blockIdx.x * 64;
    const int b    = g0 >> 12;
    const int n0   = g0 & (NPB - 1);

    share[wv][lane] = -INFINITY;
    __syncthreads();

    const float4 me = xp[g0 + lane];                 // coalesced
    const float cx = me.x, cy = me.y, cz = me.z, xxn = me.w;

    auto dist = [&](float4 q) -> float {
        float inner = __fadd_rn(__fadd_rn(__fmul_rn(cx, q.x), __fmul_rn(cy, q.y)),
                                __fmul_rn(cz, q.z));
        return __fsub_rn(__fsub_rn(__fmul_rn(2.0f, inner), xxn), q.w);
    };

    float vals[KNB];
#pragma unroll
    for (int j = 0; j < KNB; ++j) vals[j] = -INFINITY;

    const float4* cand = xp + (b << 12) + wv * SEGW; // wave-uniform -> s_load

    // warm-up: direct sorted insert of first 20 candidates
#pragma unroll 1
    for (int i = 0; i < KNB; ++i) {
        float cv = dist(cand[i]);
#pragma unroll
        for (int j = 0; j < KNB; ++j) {
            float nv = fmaxf(cv, vals[j]);
            cv       = fminf(cv, vals[j]);
            vals[j]  = nv;
        }
    }
    float vmin = vals[KNB - 1];
    float thr  = vmin;
    int   cnt  = 0;

    auto flush = [&]() {
#pragma unroll
        for (int j = 0; j < NSLOT; ++j) {
            if (!__any(j < cnt)) break;
            float cv = (j < cnt) ? sm.buf[j][tid] : -INFINITY;
#pragma unroll
            for (int q = 0; q < KNB; ++q) {          // 2-op step: max/min
                float nv = fmaxf(cv, vals[q]);
                cv       = fminf(cv, vals[q]);
                vals[q]  = nv;
            }
            vmin = vals[KNB - 1];
        }
        cnt = 0;
        thr = fmaxf(thr, vmin);
    };

    // remainder of first 64-cand chunk, buffered
#pragma unroll 1
    for (int i = KNB; i < 64; i += 4) {
#pragma unroll
        for (int u = 0; u < 4; ++u) {
            float d = dist(cand[i + u]);
            if (d > thr) { sm.buf[cnt][tid] = d; ++cnt; }
        }
        if (__any(cnt >= NSLOT - 3)) flush();        // 8 + 4 <= 12 slots
    }

    // main scan with cross-wave threshold refresh every 64 candidates
#pragma unroll 1
    for (int ii = 64; ii < SEGW; ii += 64) {
        share[wv][lane] = vmin;                      // racy: stale = safe
        float mx = share[0][lane];
#pragma unroll
        for (int w = 1; w < NSEG; ++w) mx = fmaxf(mx, share[w][lane]);
        thr = fmaxf(thr, mx);
#pragma unroll 1
        for (int i = ii; i < ii + 64; i += 4) {
#pragma unroll
            for (int u = 0; u < 4; ++u) {
                float d = dist(cand[i + u]);
                if (d > thr) { sm.buf[cnt][tid] = d; ++cnt; }
            }
            if (__any(cnt >= NSLOT - 3)) flush();
        }
    }
    flush();
    __syncthreads();                                 // retire push buffers

#pragma unroll
    for (int j = 0; j < KNB; ++j) sm.vals[wv][j][lane] = vals[j];
    __syncthreads();

    // every wave redundantly merges the 8 sorted value lists -> t (20th)
    float t = -INFINITY;
    {
        int p0 = 0, p1 = 0, p2 = 0, p3 = 0, p4 = 0, p5 = 0, p6 = 0, p7 = 0;
#pragma unroll 1
        for (int k = 0; k < KNB; ++k) {
            float e0 = sm.vals[0][p0][lane], e1 = sm.vals[1][p1][lane];
            float e2 = sm.vals[2][p2][lane], e3 = sm.vals[3][p3][lane];
            float e4 = sm.vals[4][p4][lane], e5 = sm.vals[5][p5][lane];
            float e6 = sm.vals[6][p6][lane], e7 = sm.vals[7][p7][lane];
            float bv = e0; int bs = 0;
            if (e1 > bv) { bv = e1; bs = 1; }
            if (e2 > bv) { bv = e2; bs = 2; }
            if (e3 > bv) { bv = e3; bs = 3; }
            if (e4 > bv) { bv = e4; bs = 4; }
            if (e5 > bv) { bv = e5; bs = 5; }
            if (e6 > bv) { bv = e6; bs = 6; }
            if (e7 > bv) { bv = e7; bs = 7; }
            t = bv;
            p0 += (bs == 0); p1 += (bs == 1); p2 += (bs == 2); p3 += (bs == 3);
            p4 += (bs == 4); p5 += (bs == 5); p6 += (bs == 6); p7 += (bs == 7);
        }
    }
    __syncthreads();                                 // retire vals (alias b)

    // phase B: collect survivors d >= t (idx | strict-bit)
    int myc = 0;
#pragma unroll 1
    for (int i = 0; i < SEGW; i += 8) {
#pragma unroll
        for (int u = 0; u < 8; ++u) {
            float d = dist(cand[i + u]);
            if (d >= t) {
                if (myc < KNB)
                    sm.b.list[wv][lane][myc] =
                        (wv * SEGW + i + u) | ((d > t) ? (int)0x80000000 : 0);
                ++myc;
            }
        }
    }
    sm.b.cnt[wv][lane] = (myc < KNB) ? myc : KNB;
    __syncthreads();

    if (wv == 0) {
        int nout = 0;
#pragma unroll 1
        for (int pass = 0; pass < 2; ++pass) {       // 0: d>t, 1: d==t
#pragma unroll 1
            for (int w = 0; w < NSEG; ++w) {
                int cw = sm.b.cnt[w][lane];
#pragma unroll 1
                for (int j = 0; j < KNB; ++j) {
                    if (!__any(j < cw)) break;
                    if (j < cw) {
                        int e = sm.b.list[w][lane][j];
                        bool strict = (e < 0);
                        bool take = (pass == 0) ? strict : !strict;
                        if (take && nout < KNB) {
                            outk[nout][lane] = e & 0x7fffffff;
                            ++nout;
                        }
                    }
                }
            }
        }
    }
    __syncthreads();                                 // outk ready; b dead

    // ------------------- fused conv epilogue (R6-validated) -----------------
    // stage all 1280 (k,pt) neighbor difs cooperatively into sm.f.dif
#pragma unroll
    for (int r = 0; r < 3; ++r) {
        int p = tid + r * 512;
        if (p < KNB * 64) {
            int k = p >> 6, pt = p & 63;
            int nb = outk[k][pt];
            float4 nq = xp[(b << 12) + nb];              // scattered (spread)
            float4 cq = xp[g0 + pt];                     // L1-hot
            sm.f.dif[k][0][pt] = __fsub_rn(nq.x, cq.x);
            sm.f.dif[k][1][pt] = __fsub_rn(nq.y, cq.y);
            sm.f.dif[k][2][pt] = __fsub_rn(nq.z, cq.z);
        }
    }
    __syncthreads();

    float dx[KNB], dy[KNB], dz[KNB];
#pragma unroll
    for (int k = 0; k < KNB; ++k) {                      // conflict-free LDS
        dx[k] = sm.f.dif[k][0][lane];
        dy[k] = sm.f.dif[k][1][lane];
        dz[k] = sm.f.dif[k][2][lane];
    }

    // conv1 eighth: channels [8*wv, 8*wv+8)
    const float4* w1fv = (const float4*)w1f;
#pragma unroll 1
    for (int cc = 0; cc < 8; ++cc) {
        int c = wv * 8 + cc;                             // uniform -> s_load
        float4 wa = w1fv[c * 2];                         // {W0,W1,W2,W3}
        float4 wb = w1fv[c * 2 + 1];                     // {W4,W5,B1',pad}
        float base = wb.z + wa.w * cx + wb.x * cy + wb.y * cz;
        float m1 = -INFINITY, s = 0.f;
#pragma unroll
        for (int k = 0; k < KNB; ++k) {
            float h = fmaf(dz[k], wa.z, fmaf(dy[k], wa.y, fmaf(dx[k], wa.x, base)));
            float r = fmaxf(0.f, h);
            m1 = fmaxf(m1, r);
            s += r;
        }
        sm.f.cat[c * 64 + lane]        = m1;
        sm.f.cat[(64 + c) * 64 + lane] = s / 20.0f;
    }
    __syncthreads();

    const size_t SEC = (size_t)NB * 64 * NPB;   // elements per output section

    // write m1/m2 rows straight from cat (coalesced 256B rows)
#pragma unroll 1
    for (int q = 0; q < 16; ++q) {
        int r  = wv * 16 + q;                   // 0..127, uniform
        int ch = r & 63;
        float* dst = out + SEC * (1 + (r >> 6)) + ((size_t)b * 64 + ch) * NPB + n0;
        dst[lane] = sm.f.cat[r * 64 + lane];
    }

    // conv2 eighth: outputs [8*wv, 8*wv+8)
    const int ob = wv * 8;                      // uniform -> s_load weights
    float acc[8];
#pragma unroll
    for (int j = 0; j < 8; ++j) acc[j] = w2b[ob + j];
#pragma unroll 4
    for (int c = 0; c < 128; ++c) {
        float v = sm.f.cat[c * 64 + lane];
        const float4* wr = (const float4*)(w2f + c * 64 + ob);
        float4 q0 = wr[0], q1 = wr[1];
        acc[0] = fmaf(v, q0.x, acc[0]);  acc[1] = fmaf(v, q0.y, acc[1]);
        acc[2] = fmaf(v, q0.z, acc[2]);  acc[3] = fmaf(v, q0.w, acc[3]);
        acc[4] = fmaf(v, q1.x, acc[4]);  acc[5] = fmaf(v, q1.y, acc[5]);
        acc[6] = fmaf(v, q1.z, acc[6]);  acc[7] = fmaf(v, q1.w, acc[7]);
    }
#pragma unroll
    for (int j = 0; j < 8; ++j) acc[j] = fmaxf(0.f, acc[j]);

    __syncthreads();                            // all waves done reading cat
#pragma unroll
    for (int j = 0; j < 8; ++j) sm.f.cat[(ob + j) * 64 + lane] = acc[j];
    __syncthreads();
#pragma unroll 1
    for (int q = 0; q < 8; ++q) {
        int oo = wv * 8 + q;
        out[((size_t)b * 64 + oo) * NPB + n0 + lane] = sm.f.cat[oo * 64 + lane];
    }
}

extern "C" void kernel_launch(void* const* d_in, const int* in_sizes, int n_in,
                              void* d_out, int out_size, void* d_ws, size_t ws_size,
                              hipStream_t stream) {
    const float* x   = (const float*)d_in[0];
    const float* w1  = (const float*)d_in[1];
    const float* b1  = (const float*)d_in[2];
    const float* g1  = (const float*)d_in[3];
    const float* be1 = (const float*)d_in[4];
    const float* rm1 = (const float*)d_in[5];
    const float* rv1 = (const float*)d_in[6];
    const float* w2  = (const float*)d_in[7];
    const float* b2  = (const float*)d_in[8];
    const float* g2  = (const float*)d_in[9];
    const float* be2 = (const float*)d_in[10];
    const float* rm2 = (const float*)d_in[11];
    const float* rv2 = (const float*)d_in[12];

    char*   ws  = (char*)d_ws;
    float4* xp  = (float4*)ws;                      // 512 KB
    float*  w1f = (float*)(ws + 512 * 1024);        // 2 KB
    float*  w2f = w1f + 64 * 8;                     // 32 KB
    float*  w2b = w2f + 64 * 128;                   // 256 B

    pack_prep_kernel<<<NPTS / 256, 256, 0, stream>>>(
        x, xp, w1, b1, g1, be1, rm1, rv1, w2, b2, g2, be2, rm2, rv2,
        w1f, w2f, w2b);
    knnfuse_kernel<<<NPTS / 64, 512, 0, stream>>>(xp, w1f, w2f, w2b,
                                                  (float*)d_out);
}

// Round 11
// 291.047 us; speedup vs baseline: 1.1627x; 1.0080x over previous
//
#include <hip/hip_runtime.h>
#include <cstddef>

#define NPB  4096            // points per batch
#define KNB  20              // neighbors
#define NB   8               // batches
#define NPTS (NB * NPB)      // 32768 total points
#define NSEG 8               // segment-waves per block
#define SEGW 512             // candidates per segment
#define NSLOT 16             // push-buffer slots per thread

// ---------------------------------------------------------------------------
// Kernel A+P: pack (x,y,z,xx) float4 (512 KB, L2-resident) + block 0 folds
// BN into conv weights. xx arithmetic identical to reference numpy fp32.
// (R9-validated)
// ---------------------------------------------------------------------------
__global__ __launch_bounds__(256) void pack_prep_kernel(
    const float* __restrict__ x, float4* __restrict__ xp,
    const float* __restrict__ w1, const float* __restrict__ b1,
    const float* __restrict__ g1, const float* __restrict__ be1,
    const float* __restrict__ rm1, const float* __restrict__ rv1,
    const float* __restrict__ w2, const float* __restrict__ b2,
    const float* __restrict__ g2, const float* __restrict__ be2,
    const float* __restrict__ rm2, const float* __restrict__ rv2,
    float* __restrict__ w1f, float* __restrict__ w2f, float* __restrict__ w2b)
{
    const int tid = threadIdx.x;
    const int g = blockIdx.x * 256 + tid;
    const int b = g >> 12, n = g & (NPB - 1);
    const float* xb = x + (size_t)b * 3 * NPB;
    float a0 = xb[n], a1 = xb[NPB + n], a2 = xb[2 * NPB + n];
    float xx = __fadd_rn(__fadd_rn(__fmul_rn(a0, a0), __fmul_rn(a1, a1)),
                         __fmul_rn(a2, a2));
    xp[g] = make_float4(a0, a1, a2, xx);

    if (blockIdx.x == 0) {
        if (tid < 64) {
            float sc1 = g1[tid] * rsqrtf(rv1[tid] + 1e-5f);
            float sh1 = be1[tid] - rm1[tid] * sc1;
#pragma unroll
            for (int j = 0; j < 6; ++j) w1f[tid * 8 + j] = sc1 * w1[tid * 6 + j];
            w1f[tid * 8 + 6] = sc1 * b1[tid] + sh1;
            w1f[tid * 8 + 7] = 0.f;
            float sc2 = g2[tid] * rsqrtf(rv2[tid] + 1e-5f);
            w2b[tid] = sc2 * b2[tid] + (be2[tid] - rm2[tid] * sc2);
        }
        for (int i = tid; i < 64 * 128; i += 256) {
            int c = i >> 6, o = i & 63;
            float sc2 = g2[o] * rsqrtf(rv2[o] + 1e-5f);
            w2f[i] = sc2 * w2[o * 128 + c];
        }
    }
}

// ---------------------------------------------------------------------------
// Kernel B+C merged (R9-validated layout; scan tuned): exact top-20 SET per
// point + fused conv epilogue. Block = 512 thr = 64 points x 8 segment-waves
// (wave-uniform candidate float4 stream -> s_load broadcast).
// Scan tuning vs R9: NSLOT 16, flush check every 8 cands (<=8 resident + 8
// pushed = 16 slots), cross-wave threshold refresh every 32 cands.
// ---------------------------------------------------------------------------
union KSMem {
    float buf[NSLOT][512];          // 32 KB scan push buffers [slot][tid]
    float vals[NSEG][KNB][64];      // 40 KB sorted partial lists [wave][j][pt]
    struct {
        int list[NSEG][64][21];     // 42 KB survivors idx|(strict<<31)
        int cnt[NSEG][64];          //  2 KB
    } b;                            // 44 KB
    struct {
        float cat[128 * 64];        // 32 KB [c][pt]: c<64 m1, c>=64 m2
        float dif[KNB][3][64];      // 15 KB [k][coord][pt]
    } f;                            // 47 KB  (union = 47 KB)
};

__global__ __launch_bounds__(512, 4) void knnfuse_kernel(
    const float4* __restrict__ xp,
    const float* __restrict__ w1f, const float* __restrict__ w2f,
    const float* __restrict__ w2b, float* __restrict__ out)
{
    __shared__ KSMem sm;
    __shared__ float share[NSEG][64];   // 2 KB cross-wave vmins
    __shared__ int   outk[KNB][64];     // 5 KB final neighbor idx [k][pt]

    const int tid  = threadIdx.x;
    const int wv   = __builtin_amdgcn_readfirstlane(tid >> 6);
    const int lane = tid & 63;
    const int g0   = blockIdx.x * 64;
    const int b    = g0 >> 12;
    const int n0   = g0 & (NPB - 1);

    share[wv][lane] = -INFINITY;
    __syncthreads();

    const float4 me = xp[g0 + lane];                 // coalesced
    const float cx = me.x, cy = me.y, cz = me.z, xxn = me.w;

    auto dist = [&](float4 q) -> float {
        float inner = __fadd_rn(__fadd_rn(__fmul_rn(cx, q.x), __fmul_rn(cy, q.y)),
                                __fmul_rn(cz, q.z));
        return __fsub_rn(__fsub_rn(__fmul_rn(2.0f, inner), xxn), q.w);
    };

    float vals[KNB];
#pragma unroll
    for (int j = 0; j < KNB; ++j) vals[j] = -INFINITY;

    const float4* cand = xp + (b << 12) + wv * SEGW; // wave-uniform -> s_load

    // warm-up: direct sorted insert of first 20 candidates
#pragma unroll 1
    for (int i = 0; i < KNB; ++i) {
        float cv = dist(cand[i]);
#pragma unroll
        for (int j = 0; j < KNB; ++j) {
            float nv = fmaxf(cv, vals[j]);
            cv       = fminf(cv, vals[j]);
            vals[j]  = nv;
        }
    }
    float vmin = vals[KNB - 1];
    float thr  = vmin;
    int   cnt  = 0;

    auto flush = [&]() {
#pragma unroll
        for (int j = 0; j < NSLOT; ++j) {
            if (!__any(j < cnt)) break;
            float cv = (j < cnt) ? sm.buf[j][tid] : -INFINITY;
#pragma unroll
            for (int q = 0; q < KNB; ++q) {          // 2-op step: max/min
                float nv = fmaxf(cv, vals[q]);
                cv       = fminf(cv, vals[q]);
                vals[q]  = nv;
            }
            vmin = vals[KNB - 1];
        }
        cnt = 0;
        thr = fmaxf(thr, vmin);
    };

    // remainder of first 64-cand chunk, buffered (<=12 resident + 4 = 16)
#pragma unroll 1
    for (int i = KNB; i < 64; i += 4) {
#pragma unroll
        for (int u = 0; u < 4; ++u) {
            float d = dist(cand[i + u]);
            if (d > thr) { sm.buf[cnt][tid] = d; ++cnt; }
        }
        if (__any(cnt >= 13)) flush();
    }
    flush();                                         // leave cnt=0 for main

    // main scan: threshold refresh every 32, flush check every 8
#pragma unroll 1
    for (int ii = 64; ii < SEGW; ii += 32) {
        share[wv][lane] = vmin;                      // racy: stale = safe
        float mx = share[0][lane];
#pragma unroll
        for (int w = 1; w < NSEG; ++w) mx = fmaxf(mx, share[w][lane]);
        thr = fmaxf(thr, mx);
#pragma unroll 1
        for (int i = ii; i < ii + 32; i += 8) {
#pragma unroll
            for (int u = 0; u < 8; ++u) {
                float d = dist(cand[i + u]);
                if (d > thr) { sm.buf[cnt][tid] = d; ++cnt; }
            }
            if (__any(cnt >= 9)) flush();            // <=8 resident + 8 = 16
        }
    }
    flush();
    __syncthreads();                                 // retire push buffers

#pragma unroll
    for (int j = 0; j < KNB; ++j) sm.vals[wv][j][lane] = vals[j];
    __syncthreads();

    // every wave redundantly merges the 8 sorted value lists -> t (20th)
    float t = -INFINITY;
    {
        int p0 = 0, p1 = 0, p2 = 0, p3 = 0, p4 = 0, p5 = 0, p6 = 0, p7 = 0;
#pragma unroll 1
        for (int k = 0; k < KNB; ++k) {
            float e0 = sm.vals[0][p0][lane], e1 = sm.vals[1][p1][lane];
            float e2 = sm.vals[2][p2][lane], e3 = sm.vals[3][p3][lane];
            float e4 = sm.vals[4][p4][lane], e5 = sm.vals[5][p5][lane];
            float e6 = sm.vals[6][p6][lane], e7 = sm.vals[7][p7][lane];
            float bv = e0; int bs = 0;
            if (e1 > bv) { bv = e1; bs = 1; }
            if (e2 > bv) { bv = e2; bs = 2; }
            if (e3 > bv) { bv = e3; bs = 3; }
            if (e4 > bv) { bv = e4; bs = 4; }
            if (e5 > bv) { bv = e5; bs = 5; }
            if (e6 > bv) { bv = e6; bs = 6; }
            if (e7 > bv) { bv = e7; bs = 7; }
            t = bv;
            p0 += (bs == 0); p1 += (bs == 1); p2 += (bs == 2); p3 += (bs == 3);
            p4 += (bs == 4); p5 += (bs == 5); p6 += (bs == 6); p7 += (bs == 7);
        }
    }
    __syncthreads();                                 // retire vals (alias b)

    // phase B: collect survivors d >= t (idx | strict-bit)
    int myc = 0;
#pragma unroll 1
    for (int i = 0; i < SEGW; i += 8) {
#pragma unroll
        for (int u = 0; u < 8; ++u) {
            float d = dist(cand[i + u]);
            if (d >= t) {
                if (myc < KNB)
                    sm.b.list[wv][lane][myc] =
                        (wv * SEGW + i + u) | ((d > t) ? (int)0x80000000 : 0);
                ++myc;
            }
        }
    }
    sm.b.cnt[wv][lane] = (myc < KNB) ? myc : KNB;
    __syncthreads();

    if (wv == 0) {
        int nout = 0;
#pragma unroll 1
        for (int pass = 0; pass < 2; ++pass) {       // 0: d>t, 1: d==t
#pragma unroll 1
            for (int w = 0; w < NSEG; ++w) {
                int cw = sm.b.cnt[w][lane];
#pragma unroll 1
                for (int j = 0; j < KNB; ++j) {
                    if (!__any(j < cw)) break;
                    if (j < cw) {
                        int e = sm.b.list[w][lane][j];
                        bool strict = (e < 0);
                        bool take = (pass == 0) ? strict : !strict;
                        if (take && nout < KNB) {
                            outk[nout][lane] = e & 0x7fffffff;
                            ++nout;
                        }
                    }
                }
            }
        }
    }
    __syncthreads();                                 // outk ready; b dead

    // ------------------- fused conv epilogue (R9-validated) -----------------
#pragma unroll
    for (int r = 0; r < 3; ++r) {
        int p = tid + r * 512;
        if (p < KNB * 64) {
            int k = p >> 6, pt = p & 63;
            int nb = outk[k][pt];
            float4 nq = xp[(b << 12) + nb];              // scattered (spread)
            float4 cq = xp[g0 + pt];                     // L1-hot
            sm.f.dif[k][0][pt] = __fsub_rn(nq.x, cq.x);
            sm.f.dif[k][1][pt] = __fsub_rn(nq.y, cq.y);
            sm.f.dif[k][2][pt] = __fsub_rn(nq.z, cq.z);
        }
    }
    __syncthreads();

    float dx[KNB], dy[KNB], dz[KNB];
#pragma unroll
    for (int k = 0; k < KNB; ++k) {                      // conflict-free LDS
        dx[k] = sm.f.dif[k][0][lane];
        dy[k] = sm.f.dif[k][1][lane];
        dz[k] = sm.f.dif[k][2][lane];
    }

    // conv1 eighth: channels [8*wv, 8*wv+8)
    const float4* w1fv = (const float4*)w1f;
#pragma unroll 1
    for (int cc = 0; cc < 8; ++cc) {
        int c = wv * 8 + cc;                             // uniform -> s_load
        float4 wa = w1fv[c * 2];                         // {W0,W1,W2,W3}
        float4 wb = w1fv[c * 2 + 1];                     // {W4,W5,B1',pad}
        float base = wb.z + wa.w * cx + wb.x * cy + wb.y * cz;
        float m1 = -INFINITY, s = 0.f;
#pragma unroll
        for (int k = 0; k < KNB; ++k) {
            float h = fmaf(dz[k], wa.z, fmaf(dy[k], wa.y, fmaf(dx[k], wa.x, base)));
            float r = fmaxf(0.f, h);
            m1 = fmaxf(m1, r);
            s += r;
        }
        sm.f.cat[c * 64 + lane]        = m1;
        sm.f.cat[(64 + c) * 64 + lane] = s / 20.0f;
    }
    __syncthreads();

    const size_t SEC = (size_t)NB * 64 * NPB;   // elements per output section

    // write m1/m2 rows straight from cat (coalesced 256B rows)
#pragma unroll 1
    for (int q = 0; q < 16; ++q) {
        int r  = wv * 16 + q;                   // 0..127, uniform
        int ch = r & 63;
        float* dst = out + SEC * (1 + (r >> 6)) + ((size_t)b * 64 + ch) * NPB + n0;
        dst[lane] = sm.f.cat[r * 64 + lane];
    }

    // conv2 eighth: outputs [8*wv, 8*wv+8)
    const int ob = wv * 8;                      // uniform -> s_load weights
    float acc[8];
#pragma unroll
    for (int j = 0; j < 8; ++j) acc[j] = w2b[ob + j];
#pragma unroll 4
    for (int c = 0; c < 128; ++c) {
        float v = sm.f.cat[c * 64 + lane];
        const float4* wr = (const float4*)(w2f + c * 64 + ob);
        float4 q0 = wr[0], q1 = wr[1];
        acc[0] = fmaf(v, q0.x, acc[0]);  acc[1] = fmaf(v, q0.y, acc[1]);
        acc[2] = fmaf(v, q0.z, acc[2]);  acc[3] = fmaf(v, q0.w, acc[3]);
        acc[4] = fmaf(v, q1.x, acc[4]);  acc[5] = fmaf(v, q1.y, acc[5]);
        acc[6] = fmaf(v, q1.z, acc[6]);  acc[7] = fmaf(v, q1.w, acc[7]);
    }
#pragma unroll
    for (int j = 0; j < 8; ++j) acc[j] = fmaxf(0.f, acc[j]);

    __syncthreads();                            // all waves done reading cat
#pragma unroll
    for (int j = 0; j < 8; ++j) sm.f.cat[(ob + j) * 64 + lane] = acc[j];
    __syncthreads();
#pragma unroll 1
    for (int q = 0; q < 8; ++q) {
        int oo = wv * 8 + q;
        out[((size_t)b * 64 + oo) * NPB + n0 + lane] = sm.f.cat[oo * 64 + lane];
    }
}

extern "C" void kernel_launch(void* const* d_in, const int* in_sizes, int n_in,
                              void* d_out, int out_size, void* d_ws, size_t ws_size,
                              hipStream_t stream) {
    const float* x   = (const float*)d_in[0];
    const float* w1  = (const float*)d_in[1];
    const float* b1  = (const float*)d_in[2];
    const float* g1  = (const float*)d_in[3];
    const float* be1 = (const float*)d_in[4];
    const float* rm1 = (const float*)d_in[5];
    const float* rv1 = (const float*)d_in[6];
    const float* w2  = (const float*)d_in[7];
    const float* b2  = (const float*)d_in[8];
    const float* g2  = (const float*)d_in[9];
    const float* be2 = (const float*)d_in[10];
    const float* rm2 = (const float*)d_in[11];
    const float* rv2 = (const float*)d_in[12];

    char*   ws  = (char*)d_ws;
    float4* xp  = (float4*)ws;                      // 512 KB
    float*  w1f = (float*)(ws + 512 * 1024);        // 2 KB
    float*  w2f = w1f + 64 * 8;                     // 32 KB
    float*  w2b = w2f + 64 * 128;                   // 256 B

    pack_prep_kernel<<<NPTS / 256, 256, 0, stream>>>(
        x, xp, w1, b1, g1, be1, rm1, rv1, w2, b2, g2, be2, rm2, rv2,
        w1f, w2f, w2b);
    knnfuse_kernel<<<NPTS / 64, 512, 0, stream>>>(xp, w1f, w2f, w2b,
                                                  (float*)d_out);
}